// Round 9
// baseline (758.520 us; speedup 1.0000x reference)
//
#include <hip/hip_runtime.h>

typedef unsigned short u16;
typedef unsigned int   u32;
typedef __attribute__((ext_vector_type(8))) short short8;
typedef __attribute__((ext_vector_type(4))) float f32x4;
typedef __attribute__((ext_vector_type(4))) u16  u16x4;

#define DI __device__ __forceinline__

DI float b2f(u16 v){ return __builtin_bit_cast(float, (u32)v << 16); }
DI u16 f2b(float f){ u32 u = __builtin_bit_cast(u32, f); return (u16)((u + 0x7fffu + ((u >> 16) & 1u)) >> 16); }
DI float lrelu(float v){ return v > 0.f ? v : 0.01f * v; }

// ---------------- prep: zero BN+stat accumulators + cvt + conv repack ------
__global__ __launch_bounds__(256)
void prep(float* __restrict__ partA,
          const float* __restrict__ trees, u16* __restrict__ Tb,
          const float* __restrict__ w1, u16* __restrict__ Wb1,
          const float* __restrict__ w2, u16* __restrict__ Wb2,
          const float* __restrict__ w3, u16* __restrict__ Wb3,
          const float* __restrict__ w4, u16* __restrict__ Wb4,
          const float* __restrict__ cw1, u16* __restrict__ Wr1,
          const float* __restrict__ cw2, u16* __restrict__ Wr2,
          const float* __restrict__ cw3, u16* __restrict__ Wr3)
{
  int loc = blockIdx.x*256 + threadIdx.x;
  // segment 0: zero BN part accumulators + conv3 per-sample stats (14976 f)
  if (loc < 14976){ partA[loc] = 0.f; return; }
  loc -= 14976;
  // segments 1-5: f32 -> bf16 (float4 granules)
  {
    const float* in = nullptr; u16* out = nullptr;
    if      (loc < 32768){ in = trees; out = Tb; }
    else if ((loc -= 32768) < 1024){ in = w1; out = Wb1; }
    else if ((loc -= 1024) < 4096){ in = w2; out = Wb2; }
    else if ((loc -= 4096) < 65536){ in = w3; out = Wb3; }
    else if ((loc -= 65536) < 1048576){ in = w4; out = Wb4; }
    else { loc -= 1048576; goto repack; }
    float4 v = ((const float4*)in)[loc];
    u16x4 o; o[0]=f2b(v.x); o[1]=f2b(v.y); o[2]=f2b(v.z); o[3]=f2b(v.w);
    *(u16x4*)(out + (size_t)loc*4) = o;
    return;
  }
repack:
  {
    const float* w; u16* wr; int C, lgC;
    if      (loc < 24576){ w = cw1; wr = Wr1; C = 64;  lgC = 6; }
    else if ((loc -= 24576) < 98304){ w = cw2; wr = Wr2; C = 128; lgC = 7; }
    else if ((loc -= 98304) < 393216){ w = cw3; wr = Wr3; C = 256; lgC = 8; }
    else return;
    int R = 3*C;
    int o = loc / R; int r = loc - o*R;
    int k = r >> lgC; int c = r & (C-1);
    wr[loc] = f2b(w[(size_t)o*R + c*3 + k]);
  }
}

// ---------------- GEMM (NT): Y[M,N] = A[M,K] * W[N,K]^T, f32 out -----------
template<int BM, int BN, int WROWS, int WCOLS, int RT, int CT, bool APPLYA, bool STATS, int KK>
__global__ __launch_bounds__(WROWS*WCOLS*64)
void gemm_nt(const u16* __restrict__ A, const float* __restrict__ Af,
             const u16* __restrict__ W, float* __restrict__ Y,
             const float* __restrict__ partPrev, const float* __restrict__ gP,
             const float* __restrict__ beP, float* __restrict__ partOut,
             int M, int N, int K)
{
  constexpr int NT  = WROWS*WCOLS*64;
  constexpr int ALD = (BM*4)/NT;
  constexpr int BLD = (BN*4)/NT;
  __shared__ __align__(16) u16 As[BM*32];
  __shared__ __align__(16) u16 Bs[BN*32];
  __shared__ float ssl[APPLYA ? 2*KK : 1];
  const int tid  = threadIdx.x;
  const int wave = tid >> 6, lane = tid & 63;
  const int wr = wave / WCOLS, wc = wave % WCOLS;
  const int lrow = lane & 15, kg = lane >> 4;
  const int m0 = blockIdx.x * BM, n0 = blockIdx.y * BN;

  if constexpr (APPLYA){
    for (int k = tid; k < KK; k += NT){
      float s = partPrev[k], s2 = partPrev[KK + k];
      float inv  = 1.f / (float)M;
      float mean = s * inv;
      float var  = fmaxf(s2*inv - mean*mean, 0.f);
      float sc   = gP[k] * rsqrtf(var + 1e-5f);
      ssl[k]      = sc;
      ssl[KK + k] = beP[k] - mean*sc;
    }
    __syncthreads();
  }

  f32x4 acc[RT][CT] = {};
  for (int k0 = 0; k0 < K; k0 += 32) {
    uint4 av[ALD], bv[BLD];
    if constexpr (APPLYA){
#pragma unroll
      for (int i = 0; i < ALD; i++){
        int x = tid + i*NT; int row = m0 + (x>>2); int c0 = k0 + (x&3)*8;
        const float* ap = Af + (size_t)row*K + c0;
        float4 f0 = *(const float4*)ap;
        float4 f1 = *(const float4*)(ap + 4);
        u32 p0 = (u32)f2b(lrelu(f0.x*ssl[c0+0] + ssl[KK+c0+0]))
               | ((u32)f2b(lrelu(f0.y*ssl[c0+1] + ssl[KK+c0+1])) << 16);
        u32 p1 = (u32)f2b(lrelu(f0.z*ssl[c0+2] + ssl[KK+c0+2]))
               | ((u32)f2b(lrelu(f0.w*ssl[c0+3] + ssl[KK+c0+3])) << 16);
        u32 p2 = (u32)f2b(lrelu(f1.x*ssl[c0+4] + ssl[KK+c0+4]))
               | ((u32)f2b(lrelu(f1.y*ssl[c0+5] + ssl[KK+c0+5])) << 16);
        u32 p3 = (u32)f2b(lrelu(f1.z*ssl[c0+6] + ssl[KK+c0+6]))
               | ((u32)f2b(lrelu(f1.w*ssl[c0+7] + ssl[KK+c0+7])) << 16);
        av[i] = uint4{p0, p1, p2, p3};
      }
    } else {
#pragma unroll
      for (int i = 0; i < ALD; i++){ int x = tid + i*NT; av[i] = *(const uint4*)(A + (size_t)(m0 + (x>>2))*K + k0 + (x&3)*8); }
    }
#pragma unroll
    for (int i = 0; i < BLD; i++){ int x = tid + i*NT; bv[i] = *(const uint4*)(W + (size_t)(n0 + (x>>2))*K + k0 + (x&3)*8); }
    __syncthreads();
#pragma unroll
    for (int i = 0; i < ALD; i++){ *(uint4*)(As + (tid + i*NT)*8) = av[i]; }
#pragma unroll
    for (int i = 0; i < BLD; i++){ *(uint4*)(Bs + (tid + i*NT)*8) = bv[i]; }
    __syncthreads();
    short8 af[RT], bfr[CT];
#pragma unroll
    for (int r = 0; r < RT; r++) af[r]  = *(const short8*)(As + ((wr*RT + r)*16 + lrow)*32 + kg*8);
#pragma unroll
    for (int c = 0; c < CT; c++) bfr[c] = *(const short8*)(Bs + ((wc*CT + c)*16 + lrow)*32 + kg*8);
#pragma unroll
    for (int r = 0; r < RT; r++)
#pragma unroll
      for (int c = 0; c < CT; c++)
        acc[r][c] = __builtin_amdgcn_mfma_f32_16x16x32_bf16(af[r], bfr[c], acc[r][c], 0, 0, 0);
  }
  // C/D: col=lane&15, row=(lane>>4)*4+i  [m89/m91]
#pragma unroll
  for (int r = 0; r < RT; r++)
#pragma unroll
    for (int c = 0; c < CT; c++)
#pragma unroll
      for (int i = 0; i < 4; i++){
        int m = m0 + (wr*RT + r)*16 + kg*4 + i;
        int n = n0 + (wc*CT + c)*16 + lrow;
        Y[(size_t)m*N + n] = acc[r][c][i];
      }

  if constexpr (STATS){
    __shared__ float cs[BN], cs2[BN];
    for (int t = tid; t < BN; t += NT){ cs[t] = 0.f; cs2[t] = 0.f; }
    __syncthreads();
#pragma unroll
    for (int c = 0; c < CT; c++){
      float ls = 0.f, ls2 = 0.f;
#pragma unroll
      for (int r = 0; r < RT; r++)
#pragma unroll
        for (int i = 0; i < 4; i++){ float v = acc[r][c][i]; ls += v; ls2 += v*v; }
      ls  += __shfl_down(ls, 32);  ls  += __shfl_down(ls, 16);
      ls2 += __shfl_down(ls2, 32); ls2 += __shfl_down(ls2, 16);
      if (lane < 16){
        atomicAdd(&cs [(wc*CT + c)*16 + lrow], ls);
        atomicAdd(&cs2[(wc*CT + c)*16 + lrow], ls2);
      }
    }
    __syncthreads();
    for (int t = tid; t < BN; t += NT){
      atomicAdd(partOut + n0 + t,     cs[t]);
      atomicAdd(partOut + N + n0 + t, cs2[t]);
    }
  }
}

// BN apply layer-4 (self-finalized from part4) + per-sample transpose
__global__ __launch_bounds__(256)
void bn_apply4_t(const float* __restrict__ Y, const float* __restrict__ part4,
                 const float* __restrict__ g4, const float* __restrict__ be4,
                 u16* __restrict__ Xt)
{
  const int b = blockIdx.x, tid = threadIdx.x;
  __shared__ float ssl[8192];
  __shared__ u16 t[64*65];
  for (int k = tid; k < 4096; k += 256){
    float s = part4[k], s2 = part4[4096 + k];
    float inv  = 1.f / 2048.f;
    float mean = s * inv;
    float var  = fmaxf(s2*inv - mean*mean, 0.f);
    float sc   = g4[k] * rsqrtf(var + 1e-5f);
    ssl[k]        = sc;
    ssl[4096 + k] = be4[k] - mean*sc;
  }
  __syncthreads();
  for (int j = tid; j < 4096; j += 256){
    float v = Y[(size_t)b*4096 + j];
    v = lrelu(v*ssl[j] + ssl[4096 + j]);
    int c = j >> 6, n = j & 63;
    t[c*65 + n] = f2b(v);
  }
  __syncthreads();
  for (int e = tid; e < 4096; e += 256){
    int n = e >> 6, c = e & 63;
    Xt[(size_t)b*4096 + n*64 + c] = t[c*65 + n];
  }
}

// ---------------- tree-conv + TreeLayerNorm + LeakyReLU (fused, conv1/2) ---
template<int C, int O, bool LAST, int S>
__global__ __launch_bounds__(512)
void conv_norm(const u16* __restrict__ Xin, long inStride,
               const u16* __restrict__ Wr,
               const float* __restrict__ cb, const int* __restrict__ gidx,
               u16* __restrict__ Xout, long outStride, float* __restrict__ Outf)
{
  constexpr int R   = 3*C;
  constexpr int CSI = C + 8;
  constexpr int XS  = 65*CSI;
  constexpr int RT  = O/128;
  constexpr int CH8 = C/8;
  __shared__ __align__(16) u16 xs[S*XS];
  __shared__ int idxs[S*192];
  __shared__ float red[S*16];
  __shared__ float res[S*2];
  const int b0 = blockIdx.x * S, tid = threadIdx.x;
  const int wave = tid >> 6, lane = tid & 63;
  const int lrow = lane & 15, kg = lane >> 4;

#pragma unroll
  for (int s = 0; s < S; s++){
    const u16* xg = Xin + (size_t)(b0 + s)*inStride;
    u16* xd = xs + s*XS;
    for (int e = tid; e < 64*CH8; e += 512){
      int row = e / CH8, t = e % CH8;
      *(uint4*)(xd + row*CSI + t*8) = *(const uint4*)(xg + row*C + t*8);
    }
    if (tid < CH8){ uint4 z = {0,0,0,0}; *(uint4*)(xd + 64*CSI + tid*8) = z; }
    if (tid < 189) idxs[s*192 + tid] = gidx[(size_t)(b0 + s)*189 + tid] & 63;
  }
  __syncthreads();

  int jtp[S][4];
#pragma unroll
  for (int s = 0; s < S; s++)
#pragma unroll
    for (int ct = 0; ct < 4; ct++){
      int n = ct*16 + lrow;
      if (n == 0) jtp[s][ct] = 64 | (64<<7) | (64<<14);
      else        jtp[s][ct] = idxs[s*192 + 3*(n-1) + 0]
                             | (idxs[s*192 + 3*(n-1) + 1] << 7)
                             | (idxs[s*192 + 3*(n-1) + 2] << 14);
    }

  f32x4 acc[RT][4][S] = {};
#pragma unroll
  for (int k = 0; k < 3; k++){
    int rb[S][4];
#pragma unroll
    for (int s = 0; s < S; s++)
#pragma unroll
      for (int ct = 0; ct < 4; ct++)
        rb[s][ct] = s*XS + ((jtp[s][ct] >> (7*k)) & 127)*CSI + kg*8;
    const u16* wk = Wr + k*C + kg*8;
#pragma unroll 2
    for (int cc = 0; cc < C; cc += 32){
      short8 af[RT];
#pragma unroll
      for (int r = 0; r < RT; r++)
        af[r] = *(const short8*)(wk + (size_t)((wave + 8*r)*16 + lrow)*R + cc);
#pragma unroll
      for (int s = 0; s < S; s++){
        short8 bfr[4];
#pragma unroll
        for (int ct = 0; ct < 4; ct++)
          bfr[ct] = *(const short8*)(xs + rb[s][ct] + cc);
#pragma unroll
        for (int r = 0; r < RT; r++)
#pragma unroll
          for (int ct = 0; ct < 4; ct++)
            acc[r][ct][s] = __builtin_amdgcn_mfma_f32_16x16x32_bf16(af[r], bfr[ct], acc[r][ct][s], 0, 0, 0);
      }
    }
  }

  float sv[S], sv2[S];
#pragma unroll
  for (int s = 0; s < S; s++){ sv[s] = 0.f; sv2[s] = 0.f; }
#pragma unroll
  for (int r = 0; r < RT; r++)
#pragma unroll
    for (int i = 0; i < 4; i++){
      int o = (wave + 8*r)*16 + kg*4 + i;
      float bias = cb[o];
#pragma unroll
      for (int ct = 0; ct < 4; ct++){
        int n = ct*16 + lrow;
#pragma unroll
        for (int s = 0; s < S; s++){
          float v = acc[r][ct][s][i];
          if (n != 0) v += bias;
          acc[r][ct][s][i] = v;
          sv[s] += v; sv2[s] += v*v;
        }
      }
    }
#pragma unroll
  for (int s = 0; s < S; s++){
#pragma unroll
    for (int off = 32; off > 0; off >>= 1){ sv[s] += __shfl_down(sv[s], off); sv2[s] += __shfl_down(sv2[s], off); }
    if (lane == 0){ red[s*16 + wave] = sv[s]; red[s*16 + 8 + wave] = sv2[s]; }
  }
  __syncthreads();
  if (tid < S){
    float Sm = 0.f, S2 = 0.f;
    for (int w = 0; w < 8; w++){ Sm += red[tid*16 + w]; S2 += red[tid*16 + 8 + w]; }
    const float NV = (float)(O*64);
    float mean = Sm / NV;
    float var  = fmaxf(S2/NV - mean*mean, 0.f) * (NV/(NV-1.f));  // torch.std ddof=1
    float sc   = 1.f / (sqrtf(var) + 1e-5f);
    res[tid*2 + 0] = mean; res[tid*2 + 1] = sc;
  }
  __syncthreads();

#pragma unroll
  for (int s = 0; s < S; s++){
    const float mean = res[s*2 + 0], sc = res[s*2 + 1];
    if constexpr (LAST) {
#pragma unroll
      for (int r = 0; r < RT; r++)
#pragma unroll
        for (int ct = 0; ct < 4; ct++)
#pragma unroll
          for (int i = 0; i < 4; i++){
            int o = (wave + 8*r)*16 + kg*4 + i;
            int n = ct*16 + lrow;
            Outf[(size_t)(b0 + s)*(O*64) + o*64 + n] = lrelu((acc[r][ct][s][i] - mean)*sc);
          }
    } else {
#pragma unroll
      for (int r = 0; r < RT; r++)
#pragma unroll
        for (int ct = 0; ct < 4; ct++){
          int o0 = (wave + 8*r)*16 + kg*4;
          int n  = ct*16 + lrow;
          u16x4 pk;
#pragma unroll
          for (int i = 0; i < 4; i++) pk[i] = f2b(lrelu((acc[r][ct][s][i] - mean)*sc));
          *(u16x4*)(Xout + (size_t)(b0 + s)*outStride + (size_t)n*O + o0) = pk;
        }
    }
  }
}

// ---------------- conv3 split, part 1: conv + bias + stats, bf16 out -------
// Block = (sample b, O-half h). acc = 32 floats/thread -> forced 4 waves/EU.
// Writes pre-norm bf16 node-major (stride NO) + per-sample sum/sumsq via TWO
// atomicAdds (commutative -> deterministic).
template<int C, int OH, int NO>
__global__ __launch_bounds__(512, 4)
void conv_part(const u16* __restrict__ Xin, long inStride,
               const u16* __restrict__ Wr,
               const float* __restrict__ cb, const int* __restrict__ gidx,
               u16* __restrict__ Xout, long outStride, float* __restrict__ st)
{
  constexpr int R   = 3*C;
  constexpr int CSI = C + 8;
  constexpr int RT  = OH/128;
  constexpr int CH8 = C/8;
  constexpr int HALVES = NO/OH;
  __shared__ __align__(16) u16 xs[65*CSI];
  __shared__ int idxs[192];
  __shared__ float red[16];
  const int b = blockIdx.x / HALVES, h = blockIdx.x % HALVES;
  const int tid = threadIdx.x;
  const int wave = tid >> 6, lane = tid & 63;
  const int lrow = lane & 15, kg = lane >> 4;

  const u16* xg = Xin + (size_t)b*inStride;
  for (int e = tid; e < 64*CH8; e += 512){
    int row = e / CH8, t = e % CH8;
    *(uint4*)(xs + row*CSI + t*8) = *(const uint4*)(xg + row*C + t*8);
  }
  if (tid < CH8){ uint4 z = {0,0,0,0}; *(uint4*)(xs + 64*CSI + tid*8) = z; }
  if (tid < 189) idxs[tid] = gidx[(size_t)b*189 + tid] & 63;
  __syncthreads();

  int jtp[4];
#pragma unroll
  for (int ct = 0; ct < 4; ct++){
    int n = ct*16 + lrow;
    if (n == 0) jtp[ct] = 64 | (64<<7) | (64<<14);
    else        jtp[ct] = idxs[3*(n-1) + 0] | (idxs[3*(n-1) + 1] << 7) | (idxs[3*(n-1) + 2] << 14);
  }

  f32x4 acc[RT][4] = {};
#pragma unroll
  for (int k = 0; k < 3; k++){
    int rb[4];
#pragma unroll
    for (int ct = 0; ct < 4; ct++)
      rb[ct] = ((jtp[ct] >> (7*k)) & 127)*CSI + kg*8;
    const u16* wk = Wr + (size_t)(h*OH)*R + k*C + kg*8;
#pragma unroll 2
    for (int cc = 0; cc < C; cc += 32){
      short8 af[RT];
#pragma unroll
      for (int r = 0; r < RT; r++)
        af[r] = *(const short8*)(wk + (size_t)((wave + 8*r)*16 + lrow)*R + cc);
      short8 bfr[4];
#pragma unroll
      for (int ct = 0; ct < 4; ct++)
        bfr[ct] = *(const short8*)(xs + rb[ct] + cc);
#pragma unroll
      for (int r = 0; r < RT; r++)
#pragma unroll
        for (int ct = 0; ct < 4; ct++)
          acc[r][ct] = __builtin_amdgcn_mfma_f32_16x16x32_bf16(af[r], bfr[ct], acc[r][ct], 0, 0, 0);
    }
  }

  // bias (skip null column 0) + partial stats + bf16 store (node-major, NO)
  float sv = 0.f, sv2 = 0.f;
  u16* xo = Xout + (size_t)b*outStride + h*OH;
#pragma unroll
  for (int r = 0; r < RT; r++)
#pragma unroll
    for (int ct = 0; ct < 4; ct++){
      int o0 = (wave + 8*r)*16 + kg*4;
      int n  = ct*16 + lrow;
      u16x4 pk;
#pragma unroll
      for (int i = 0; i < 4; i++){
        float bias = cb[h*OH + o0 + i];
        float v = acc[r][ct][i];
        if (n != 0) v += bias;
        pk[i] = f2b(v);
        sv += v; sv2 += v*v;
      }
      *(u16x4*)(xo + (size_t)n*NO + o0) = pk;
    }
#pragma unroll
  for (int off = 32; off > 0; off >>= 1){ sv += __shfl_down(sv, off); sv2 += __shfl_down(sv2, off); }
  if (lane == 0){ red[wave] = sv; red[8 + wave] = sv2; }
  __syncthreads();
  if (tid == 0){
    float S = 0.f, S2 = 0.f;
    for (int w = 0; w < 8; w++){ S += red[w]; S2 += red[8 + w]; }
    atomicAdd(&st[b*2 + 0], S);
    atomicAdd(&st[b*2 + 1], S2);
  }
}

// ---------------- conv3 split, part 2: TreeLayerNorm + lrelu -> f32 --------
// NOTE on stats rounding: stats were computed from f32 acc values (pre-bf16),
// values re-read here are bf16-rounded — error <= ~0.01 abs, within margin.
template<int NO>
__global__ __launch_bounds__(512)
void tnorm_apply(const u16* __restrict__ Xin, long inStride,
                 const float* __restrict__ st, float* __restrict__ Outf)
{
  constexpr int ROWP = NO + 8;
  const int b = blockIdx.x, tid = threadIdx.x;
  __shared__ u16 lds[64*ROWP];
  const u16* xg = Xin + (size_t)b*inStride;
  // stage (64, NO) node-major slice
  for (int i = 0; i < (64*NO/8)/512; i++){
    int idx = tid + i*512;             // uint4 index
    int row = idx / (NO/8), c8 = idx % (NO/8);
    *(uint4*)(lds + row*ROWP + c8*8) = *(const uint4*)(xg + row*NO + c8*8);
  }
  float S = st[b*2], S2 = st[b*2 + 1];
  const float NV = (float)(NO*64);
  float mean = S / NV;
  float var  = fmaxf(S2/NV - mean*mean, 0.f) * (NV/(NV-1.f));  // ddof=1
  float sc   = 1.f / (sqrtf(var) + 1e-5f);
  __syncthreads();
  float* out = Outf + (size_t)b*(NO*64);
  for (int j = 0; j < 64*NO/512; j++){
    int w = tid + j*512;               // output index o*64+n
    int o = w >> 6, n = w & 63;
    float v = b2f(lds[n*ROWP + o]);
    out[w] = lrelu((v - mean)*sc);
  }
}

// ---------------------------------------------------------------------------
extern "C" void kernel_launch(void* const* d_in, const int* in_sizes, int n_in,
                              void* d_out, int out_size, void* d_ws, size_t ws_size,
                              hipStream_t stream)
{
  const float* trees = (const float*)d_in[0];
  const int*   gidx  = (const int*)d_in[1];
  const float* w1 = (const float*)d_in[2];
  const float* g1 = (const float*)d_in[4];  const float* be1 = (const float*)d_in[5];
  const float* w2 = (const float*)d_in[6];
  const float* g2 = (const float*)d_in[8];  const float* be2 = (const float*)d_in[9];
  const float* w3 = (const float*)d_in[10];
  const float* g3 = (const float*)d_in[12]; const float* be3 = (const float*)d_in[13];
  const float* w4 = (const float*)d_in[14];
  const float* g4 = (const float*)d_in[16]; const float* be4 = (const float*)d_in[17];
  const float* cw1 = (const float*)d_in[18]; const float* cb1 = (const float*)d_in[19];
  const float* cw2 = (const float*)d_in[20]; const float* cb2 = (const float*)d_in[21];
  const float* cw3 = (const float*)d_in[22]; const float* cb3 = (const float*)d_in[23];

  // ws (~33.7 MiB): repacked conv weights + BN/stat accumulators + Xc2.
  char* ws = (char*)d_ws;
  size_t off = 0;
  auto alloc = [&](size_t bytes)->char*{ char* p = ws + off; off += (bytes + 255) & ~(size_t)255; return p; };
  u16*   Wr1  = (u16*)  alloc(128*192*2);
  u16*   Wr2  = (u16*)  alloc(256*384*2);
  u16*   Wr3  = (u16*)  alloc(512*768*2);
  float* partA= (float*)alloc((10880 + 4096)*4);   // BN parts + conv3 stats
  u16*   Xc2  = (u16*)  alloc((size_t)2048*64*128*2);   // 32 MiB
  float* part1 = partA;             // 128 floats
  float* part2 = part1 + 2*64;      // 512
  float* part3 = part2 + 2*256;     // 2048
  float* part4 = part3 + 2*1024;    // 8192
  float* st3   = partA + 10880;     // 4096 (2048 samples x {sum, sumsq})

  // d_out scratch layout (256 MiB f32 output buffer)
  float* outF = (float*)d_out;
  u16*   ob   = (u16*)d_out;                 // u16-unit view
  float* Yb   = (float*)ob;                  // [0, 16,777,216)   L2/L4 out
  float* Ya   = (float*)(ob + 16777216);     // [.., 20,971,520)  L1/L3 out
  u16*   Tb   = ob + 20971520;
  u16*   Wb1  = ob + 21102592;
  u16*   Wb2  = ob + 21106688;
  u16*   Wb3  = ob + 21123072;
  u16*   Wb4  = ob + 21385216;
  u16*   Xt1  = ob + 25579520;               // [.., 33,968,128)
  // Per-sample slices of d_out (65,536 u16 each):
  //   Xc3 at slice offset [0, 16,384)       (conv2 out, conv3 in)
  //   Xc4 at slice offset [16,384, 49,152)  (conv_part bf16 out)
  // tnorm_apply stages Xc4 to LDS, then overwrites the whole slice with f32.
  u16*   Xc3  = ob;                          // stride 65,536 u16
  u16*   Xc4  = ob + 16384;                  // stride 65,536 u16

  prep<<<6575, 256, 0, stream>>>(partA,
                                 trees, Tb, w1, Wb1, w2, Wb2, w3, Wb3, w4, Wb4,
                                 cw1, Wr1, cw2, Wr2, cw3, Wr3);

  gemm_nt<64,64,4,1,1,4,false,true,0><<<dim3(32,1), 256, 0, stream>>>(
      Tb, nullptr, Wb1, Ya, nullptr, nullptr, nullptr, part1, 2048, 64, 64);
  gemm_nt<64,64,4,1,1,4,true,true,64><<<dim3(32,4), 256, 0, stream>>>(
      nullptr, Ya, Wb2, Yb, part1, g1, be1, part2, 2048, 256, 64);
  gemm_nt<64,64,4,1,1,4,true,true,256><<<dim3(32,16), 256, 0, stream>>>(
      nullptr, Yb, Wb3, Ya, part2, g2, be2, part3, 2048, 1024, 256);
  gemm_nt<128,128,2,2,4,4,true,true,1024><<<dim3(16,32), 256, 0, stream>>>(
      nullptr, Ya, Wb4, Yb, part3, g3, be3, part4, 2048, 4096, 1024);
  bn_apply4_t<<<2048, 256, 0, stream>>>(Yb, part4, g4, be4, Xt1);

  // conv1: Xt1 (d_out) -> Xc2 (ws)
  conv_norm< 64,128,false,4><<< 512, 512, 0, stream>>>(Xt1, 4096, Wr1, cb1, gidx, Xc2, 8192, nullptr);
  // conv2: Xc2 (ws) -> Xc3 slices (d_out)
  conv_norm<128,256,false,4><<< 512, 512, 0, stream>>>(Xc2, 8192, Wr2, cb2, gidx, Xc3, 65536, nullptr);
  // conv3 split: conv_part (per sample-half) -> tnorm_apply (per sample)
  conv_part<256,256,512><<<4096, 512, 0, stream>>>(Xc3, 65536, Wr3, cb3, gidx, Xc4, 65536, st3);
  tnorm_apply<512><<<2048, 512, 0, stream>>>(Xc4, 65536, st3, outF);
}

// Round 10
// 581.668 us; speedup vs baseline: 1.3040x; 1.3040x over previous
//
#include <hip/hip_runtime.h>

typedef unsigned short u16;
typedef unsigned int   u32;
typedef __attribute__((ext_vector_type(8))) short short8;
typedef __attribute__((ext_vector_type(4))) float f32x4;
typedef __attribute__((ext_vector_type(4))) u16  u16x4;

#define DI __device__ __forceinline__

DI float b2f(u16 v){ return __builtin_bit_cast(float, (u32)v << 16); }
DI u16 f2b(float f){ u32 u = __builtin_bit_cast(u32, f); return (u16)((u + 0x7fffu + ((u >> 16) & 1u)) >> 16); }
DI float lrelu(float v){ return v > 0.f ? v : 0.01f * v; }

// ---------------- prep: zero BN accumulators + f32->bf16 cvt + conv repack -
// Conv weights are repacked into MFMA-FRAGMENT-TILED layout:
//   dest u16 index d: ci=d&7, lane=(d>>3)&63, blk=d>>9
//   o_tile = blk/(R/32), kbi = blk%(R/32)
//   o = o_tile*16 + (lane&15), ch = kbi*32 + (lane>>4)*8 + ci, k=ch>>lgC, c=ch&(C-1)
//   value = w[o*R + c*3 + k]
// A wave's fragment load is then 64 lanes x consecutive 16B (fully coalesced),
// and the k-loop walks contiguous 1KB tiles. (R9 lesson: the old row-major
// layout made every weight load touch 64 distinct 64B lines -> ~12TB/s eff.)
__global__ __launch_bounds__(256)
void prep(float* __restrict__ partA,
          const float* __restrict__ trees, u16* __restrict__ Tb,
          const float* __restrict__ w1, u16* __restrict__ Wb1,
          const float* __restrict__ w2, u16* __restrict__ Wb2,
          const float* __restrict__ w3, u16* __restrict__ Wb3,
          const float* __restrict__ w4, u16* __restrict__ Wb4,
          const float* __restrict__ cw1, u16* __restrict__ Wr1,
          const float* __restrict__ cw2, u16* __restrict__ Wr2,
          const float* __restrict__ cw3, u16* __restrict__ Wr3)
{
  int loc = blockIdx.x*256 + threadIdx.x;
  // segment 0: zero the stats accumulators (10880 floats)
  if (loc < 10880){ partA[loc] = 0.f; return; }
  loc -= 10880;
  // segments 1-5: f32 -> bf16 (float4 granules)
  {
    const float* in = nullptr; u16* out = nullptr;
    if      (loc < 32768){ in = trees; out = Tb; }
    else if ((loc -= 32768) < 1024){ in = w1; out = Wb1; }
    else if ((loc -= 1024) < 4096){ in = w2; out = Wb2; }
    else if ((loc -= 4096) < 65536){ in = w3; out = Wb3; }
    else if ((loc -= 65536) < 1048576){ in = w4; out = Wb4; }
    else { loc -= 1048576; goto repack; }
    float4 v = ((const float4*)in)[loc];
    u16x4 o; o[0]=f2b(v.x); o[1]=f2b(v.y); o[2]=f2b(v.z); o[3]=f2b(v.w);
    *(u16x4*)(out + (size_t)loc*4) = o;
    return;
  }
repack:
  {
    const float* w; u16* wr; int C, lgC;
    if      (loc < 24576){ w = cw1; wr = Wr1; C = 64;  lgC = 6; }
    else if ((loc -= 24576) < 98304){ w = cw2; wr = Wr2; C = 128; lgC = 7; }
    else if ((loc -= 98304) < 393216){ w = cw3; wr = Wr3; C = 256; lgC = 8; }
    else return;
    int R   = 3*C;
    int nkb = R >> 5;                 // R/32 (6, 12, 24)
    int ci   = loc & 7;
    int lane = (loc >> 3) & 63;
    int blk  = loc >> 9;
    int o_tile = blk / nkb;
    int kbi    = blk - o_tile*nkb;
    int o  = o_tile*16 + (lane & 15);
    int ch = kbi*32 + (lane >> 4)*8 + ci;
    int k  = ch >> lgC;
    int c  = ch & (C-1);
    wr[loc] = f2b(w[(size_t)o*R + c*3 + k]);
  }
}

// ---------------- GEMM (NT): Y[M,N] = A[M,K] * W[N,K]^T, f32 out -----------
// APPLYA (KK>0): A comes as f32 (prev layer's pre-BN Y). Each block first
//   SELF-FINALIZES the previous layer's BN from partPrev/gP/beP into LDS
//   ssl[2*KK] (bit-identical math to a separate bn_finalize kernel), then
//   staging applies v*sc+sh, lrelu, bf16-cast.
// STATS: per-block column sums/sumsq of the f32 output -> atomicAdd into
//   partOut [sum(N), sumsq(N)] (zeroed in prep each replay).
template<int BM, int BN, int WROWS, int WCOLS, int RT, int CT, bool APPLYA, bool STATS, int KK>
__global__ __launch_bounds__(WROWS*WCOLS*64)
void gemm_nt(const u16* __restrict__ A, const float* __restrict__ Af,
             const u16* __restrict__ W, float* __restrict__ Y,
             const float* __restrict__ partPrev, const float* __restrict__ gP,
             const float* __restrict__ beP, float* __restrict__ partOut,
             int M, int N, int K)
{
  constexpr int NT  = WROWS*WCOLS*64;
  constexpr int ALD = (BM*4)/NT;
  constexpr int BLD = (BN*4)/NT;
  __shared__ __align__(16) u16 As[BM*32];
  __shared__ __align__(16) u16 Bs[BN*32];
  __shared__ float ssl[APPLYA ? 2*KK : 1];
  const int tid  = threadIdx.x;
  const int wave = tid >> 6, lane = tid & 63;
  const int wr = wave / WCOLS, wc = wave % WCOLS;
  const int lrow = lane & 15, kg = lane >> 4;
  const int m0 = blockIdx.x * BM, n0 = blockIdx.y * BN;

  if constexpr (APPLYA){
    for (int k = tid; k < KK; k += NT){
      float s = partPrev[k], s2 = partPrev[KK + k];
      float inv  = 1.f / (float)M;
      float mean = s * inv;
      float var  = fmaxf(s2*inv - mean*mean, 0.f);
      float sc   = gP[k] * rsqrtf(var + 1e-5f);
      ssl[k]      = sc;
      ssl[KK + k] = beP[k] - mean*sc;
    }
    __syncthreads();
  }

  f32x4 acc[RT][CT] = {};
  for (int k0 = 0; k0 < K; k0 += 32) {
    uint4 av[ALD], bv[BLD];
    if constexpr (APPLYA){
#pragma unroll
      for (int i = 0; i < ALD; i++){
        int x = tid + i*NT; int row = m0 + (x>>2); int c0 = k0 + (x&3)*8;
        const float* ap = Af + (size_t)row*K + c0;
        float4 f0 = *(const float4*)ap;
        float4 f1 = *(const float4*)(ap + 4);
        u32 p0 = (u32)f2b(lrelu(f0.x*ssl[c0+0] + ssl[KK+c0+0]))
               | ((u32)f2b(lrelu(f0.y*ssl[c0+1] + ssl[KK+c0+1])) << 16);
        u32 p1 = (u32)f2b(lrelu(f0.z*ssl[c0+2] + ssl[KK+c0+2]))
               | ((u32)f2b(lrelu(f0.w*ssl[c0+3] + ssl[KK+c0+3])) << 16);
        u32 p2 = (u32)f2b(lrelu(f1.x*ssl[c0+4] + ssl[KK+c0+4]))
               | ((u32)f2b(lrelu(f1.y*ssl[c0+5] + ssl[KK+c0+5])) << 16);
        u32 p3 = (u32)f2b(lrelu(f1.z*ssl[c0+6] + ssl[KK+c0+6]))
               | ((u32)f2b(lrelu(f1.w*ssl[c0+7] + ssl[KK+c0+7])) << 16);
        av[i] = uint4{p0, p1, p2, p3};
      }
    } else {
#pragma unroll
      for (int i = 0; i < ALD; i++){ int x = tid + i*NT; av[i] = *(const uint4*)(A + (size_t)(m0 + (x>>2))*K + k0 + (x&3)*8); }
    }
#pragma unroll
    for (int i = 0; i < BLD; i++){ int x = tid + i*NT; bv[i] = *(const uint4*)(W + (size_t)(n0 + (x>>2))*K + k0 + (x&3)*8); }
    __syncthreads();
#pragma unroll
    for (int i = 0; i < ALD; i++){ *(uint4*)(As + (tid + i*NT)*8) = av[i]; }
#pragma unroll
    for (int i = 0; i < BLD; i++){ *(uint4*)(Bs + (tid + i*NT)*8) = bv[i]; }
    __syncthreads();
    short8 af[RT], bfr[CT];
#pragma unroll
    for (int r = 0; r < RT; r++) af[r]  = *(const short8*)(As + ((wr*RT + r)*16 + lrow)*32 + kg*8);
#pragma unroll
    for (int c = 0; c < CT; c++) bfr[c] = *(const short8*)(Bs + ((wc*CT + c)*16 + lrow)*32 + kg*8);
#pragma unroll
    for (int r = 0; r < RT; r++)
#pragma unroll
      for (int c = 0; c < CT; c++)
        acc[r][c] = __builtin_amdgcn_mfma_f32_16x16x32_bf16(af[r], bfr[c], acc[r][c], 0, 0, 0);
  }
  // C/D: col=lane&15, row=(lane>>4)*4+i  [m89/m91]
#pragma unroll
  for (int r = 0; r < RT; r++)
#pragma unroll
    for (int c = 0; c < CT; c++)
#pragma unroll
      for (int i = 0; i < 4; i++){
        int m = m0 + (wr*RT + r)*16 + kg*4 + i;
        int n = n0 + (wc*CT + c)*16 + lrow;
        Y[(size_t)m*N + n] = acc[r][c][i];
      }

  if constexpr (STATS){
    __shared__ float cs[BN], cs2[BN];
    for (int t = tid; t < BN; t += NT){ cs[t] = 0.f; cs2[t] = 0.f; }
    __syncthreads();
#pragma unroll
    for (int c = 0; c < CT; c++){
      float ls = 0.f, ls2 = 0.f;
#pragma unroll
      for (int r = 0; r < RT; r++)
#pragma unroll
        for (int i = 0; i < 4; i++){ float v = acc[r][c][i]; ls += v; ls2 += v*v; }
      ls  += __shfl_down(ls, 32);  ls  += __shfl_down(ls, 16);
      ls2 += __shfl_down(ls2, 32); ls2 += __shfl_down(ls2, 16);
      if (lane < 16){
        atomicAdd(&cs [(wc*CT + c)*16 + lrow], ls);
        atomicAdd(&cs2[(wc*CT + c)*16 + lrow], ls2);
      }
    }
    __syncthreads();
    for (int t = tid; t < BN; t += NT){
      atomicAdd(partOut + n0 + t,     cs[t]);
      atomicAdd(partOut + N + n0 + t, cs2[t]);
    }
  }
}

// BN apply layer-4 (self-finalized from part4) + per-sample transpose:
// Xt[b][n][c] = lrelu(bn(h4))[b][c*64+n]
__global__ __launch_bounds__(256)
void bn_apply4_t(const float* __restrict__ Y, const float* __restrict__ part4,
                 const float* __restrict__ g4, const float* __restrict__ be4,
                 u16* __restrict__ Xt)
{
  const int b = blockIdx.x, tid = threadIdx.x;
  __shared__ float ssl[8192];
  __shared__ u16 t[64*65];
  for (int k = tid; k < 4096; k += 256){
    float s = part4[k], s2 = part4[4096 + k];
    float inv  = 1.f / 2048.f;
    float mean = s * inv;
    float var  = fmaxf(s2*inv - mean*mean, 0.f);
    float sc   = g4[k] * rsqrtf(var + 1e-5f);
    ssl[k]        = sc;
    ssl[4096 + k] = be4[k] - mean*sc;
  }
  __syncthreads();
  for (int j = tid; j < 4096; j += 256){
    float v = Y[(size_t)b*4096 + j];
    v = lrelu(v*ssl[j] + ssl[4096 + j]);
    int c = j >> 6, n = j & 63;
    t[c*65 + n] = f2b(v);
  }
  __syncthreads();
  for (int e = tid; e < 4096; e += 256){
    int n = e >> 6, c = e & 63;
    Xt[(size_t)b*4096 + n*64 + c] = t[c*65 + n];
  }
}

// ---------------- tree-conv + TreeLayerNorm + LeakyReLU --------------------
// S samples per block, 8 waves. Weight fragments reused across S samples.
// Weights are in the fragment-tiled layout (see prep): a wave's af[r] load is
// Wr + o_tile*R*16 + (k*C+cc)*16 + lane*8 — fully coalesced, contiguous walk.
template<int C, int O, bool LAST, int S>
__global__ __launch_bounds__(512)
void conv_norm(const u16* __restrict__ Xin, long inStride,
               const u16* __restrict__ Wr,
               const float* __restrict__ cb, const int* __restrict__ gidx,
               u16* __restrict__ Xout, long outStride, float* __restrict__ Outf)
{
  constexpr int R   = 3*C;
  constexpr int CSI = C + 8;
  constexpr int XS  = 65*CSI;          // per-sample LDS stride (u16)
  constexpr int RT  = O/128;
  constexpr int CH8 = C/8;
  __shared__ __align__(16) u16 xs[S*XS];
  __shared__ int idxs[S*192];
  __shared__ float red[S*16];
  __shared__ float res[S*2];
  const int b0 = blockIdx.x * S, tid = threadIdx.x;
  const int wave = tid >> 6, lane = tid & 63;
  const int lrow = lane & 15, kg = lane >> 4;

#pragma unroll
  for (int s = 0; s < S; s++){
    const u16* xg = Xin + (size_t)(b0 + s)*inStride;
    u16* xd = xs + s*XS;
    for (int e = tid; e < 64*CH8; e += 512){
      int row = e / CH8, t = e % CH8;
      *(uint4*)(xd + row*CSI + t*8) = *(const uint4*)(xg + row*C + t*8);
    }
    if (tid < CH8){ uint4 z = {0,0,0,0}; *(uint4*)(xd + 64*CSI + tid*8) = z; }
    if (tid < 189) idxs[s*192 + tid] = gidx[(size_t)(b0 + s)*189 + tid] & 63;
  }
  __syncthreads();

  // packed tap indices: 7-bit fields (values 0..64), 1 VGPR per (s,ct)
  int jtp[S][4];
#pragma unroll
  for (int s = 0; s < S; s++)
#pragma unroll
    for (int ct = 0; ct < 4; ct++){
      int n = ct*16 + lrow;
      if (n == 0) jtp[s][ct] = 64 | (64<<7) | (64<<14);
      else        jtp[s][ct] = idxs[s*192 + 3*(n-1) + 0]
                             | (idxs[s*192 + 3*(n-1) + 1] << 7)
                             | (idxs[s*192 + 3*(n-1) + 2] << 14);
    }

  // per-wave weight bases (fragment-tiled layout)
  size_t wb[RT];
#pragma unroll
  for (int r = 0; r < RT; r++) wb[r] = (size_t)(wave + 8*r)*R*16 + lane*8;

  f32x4 acc[RT][4][S] = {};
#pragma unroll
  for (int k = 0; k < 3; k++){
    // per-k gather bases (u16 offsets into xs); compile-time shift
    int rb[S][4];
#pragma unroll
    for (int s = 0; s < S; s++)
#pragma unroll
      for (int ct = 0; ct < 4; ct++)
        rb[s][ct] = s*XS + ((jtp[s][ct] >> (7*k)) & 127)*CSI + kg*8;
#pragma unroll 2
    for (int cc = 0; cc < C; cc += 32){
      const int choff = (k*C + cc)*16;
      short8 af[RT];
#pragma unroll
      for (int r = 0; r < RT; r++)
        af[r] = *(const short8*)(Wr + wb[r] + choff);
#pragma unroll
      for (int s = 0; s < S; s++){
        short8 bfr[4];
#pragma unroll
        for (int ct = 0; ct < 4; ct++)
          bfr[ct] = *(const short8*)(xs + rb[s][ct] + cc);
#pragma unroll
        for (int r = 0; r < RT; r++)
#pragma unroll
          for (int ct = 0; ct < 4; ct++)
            acc[r][ct][s] = __builtin_amdgcn_mfma_f32_16x16x32_bf16(af[r], bfr[ct], acc[r][ct][s], 0, 0, 0);
      }
    }
  }

  // bias (skip null column 0) + per-sample stats over (O x 64)
  float sv[S], sv2[S];
#pragma unroll
  for (int s = 0; s < S; s++){ sv[s] = 0.f; sv2[s] = 0.f; }
#pragma unroll
  for (int r = 0; r < RT; r++)
#pragma unroll
    for (int i = 0; i < 4; i++){
      int o = (wave + 8*r)*16 + kg*4 + i;
      float bias = cb[o];
#pragma unroll
      for (int ct = 0; ct < 4; ct++){
        int n = ct*16 + lrow;
#pragma unroll
        for (int s = 0; s < S; s++){
          float v = acc[r][ct][s][i];
          if (n != 0) v += bias;
          acc[r][ct][s][i] = v;
          sv[s] += v; sv2[s] += v*v;
        }
      }
    }
#pragma unroll
  for (int s = 0; s < S; s++){
#pragma unroll
    for (int off = 32; off > 0; off >>= 1){ sv[s] += __shfl_down(sv[s], off); sv2[s] += __shfl_down(sv2[s], off); }
    if (lane == 0){ red[s*16 + wave] = sv[s]; red[s*16 + 8 + wave] = sv2[s]; }
  }
  __syncthreads();
  if (tid < S){
    float Sm = 0.f, S2 = 0.f;
    for (int w = 0; w < 8; w++){ Sm += red[tid*16 + w]; S2 += red[tid*16 + 8 + w]; }
    const float NV = (float)(O*64);
    float mean = Sm / NV;
    float var  = fmaxf(S2/NV - mean*mean, 0.f) * (NV/(NV-1.f));  // torch.std ddof=1
    float sc   = 1.f / (sqrtf(var) + 1e-5f);
    res[tid*2 + 0] = mean; res[tid*2 + 1] = sc;
  }
  __syncthreads();

#pragma unroll
  for (int s = 0; s < S; s++){
    const float mean = res[s*2 + 0], sc = res[s*2 + 1];
    if constexpr (LAST) {
#pragma unroll
      for (int r = 0; r < RT; r++)
#pragma unroll
        for (int ct = 0; ct < 4; ct++)
#pragma unroll
          for (int i = 0; i < 4; i++){
            int o = (wave + 8*r)*16 + kg*4 + i;
            int n = ct*16 + lrow;
            Outf[(size_t)(b0 + s)*(O*64) + o*64 + n] = lrelu((acc[r][ct][s][i] - mean)*sc);
          }
    } else {
#pragma unroll
      for (int r = 0; r < RT; r++)
#pragma unroll
        for (int ct = 0; ct < 4; ct++){
          int o0 = (wave + 8*r)*16 + kg*4;
          int n  = ct*16 + lrow;
          u16x4 pk;
#pragma unroll
          for (int i = 0; i < 4; i++) pk[i] = f2b(lrelu((acc[r][ct][s][i] - mean)*sc));
          *(u16x4*)(Xout + (size_t)(b0 + s)*outStride + (size_t)n*O + o0) = pk;
        }
    }
  }
}

// ---------------------------------------------------------------------------
extern "C" void kernel_launch(void* const* d_in, const int* in_sizes, int n_in,
                              void* d_out, int out_size, void* d_ws, size_t ws_size,
                              hipStream_t stream)
{
  // ALL float inputs are float32 (proven by R3's dtype-flag experiment).
  const float* trees = (const float*)d_in[0];
  const int*   gidx  = (const int*)d_in[1];
  const float* w1 = (const float*)d_in[2];
  const float* g1 = (const float*)d_in[4];  const float* be1 = (const float*)d_in[5];
  const float* w2 = (const float*)d_in[6];
  const float* g2 = (const float*)d_in[8];  const float* be2 = (const float*)d_in[9];
  const float* w3 = (const float*)d_in[10];
  const float* g3 = (const float*)d_in[12]; const float* be3 = (const float*)d_in[13];
  const float* w4 = (const float*)d_in[14];
  const float* g4 = (const float*)d_in[16]; const float* be4 = (const float*)d_in[17];
  const float* cw1 = (const float*)d_in[18]; const float* cb1 = (const float*)d_in[19];
  const float* cw2 = (const float*)d_in[20]; const float* cb2 = (const float*)d_in[21];
  const float* cw3 = (const float*)d_in[22]; const float* cb3 = (const float*)d_in[23];
  // linear biases b1..b4 cancel under training-mode BN — unused.

  // ws (~33.3 MiB): repacked conv weights + BN stat accumulators + Xc2.
  // Wr3 MUST be in ws (read by the final conv while d_out is being rewritten).
  // Xc2 MUST be in ws (conv2's slice-writes to d_out would race other blocks'
  // Xc2 reads if Xc2 lived in d_out).
  char* ws = (char*)d_ws;
  size_t off = 0;
  auto alloc = [&](size_t bytes)->char*{ char* p = ws + off; off += (bytes + 255) & ~(size_t)255; return p; };
  u16*   Wr1  = (u16*)  alloc(128*192*2);
  u16*   Wr2  = (u16*)  alloc(256*384*2);
  u16*   Wr3  = (u16*)  alloc(512*768*2);
  float* partA= (float*)alloc(2*(64+256+1024+4096)*4);  // all 4 layers, contiguous
  u16*   Xc2  = (u16*)  alloc((size_t)2048*64*128*2);   // 32 MiB
  float* part1 = partA;             // 128 floats
  float* part2 = part1 + 2*64;      // 512
  float* part3 = part2 + 2*256;     // 2048
  float* part4 = part3 + 2*1024;    // 8192

  // d_out is (2048,512,64) FLOAT32 = 256 MiB. Host MLP-phase scratch inside it.
  // Y ping-pong: Ya holds L1/L3 outputs, Yb holds L2/L4 (a layer reads the
  // previous layer's f32 output while writing its own).
  float* outF = (float*)d_out;
  u16*   ob   = (u16*)d_out;                 // u16-unit view for offsets
  float* Yb   = (float*)ob;                  // u16 [0, 16,777,216)   L2/L4 out
  float* Ya   = (float*)(ob + 16777216);     // [.., 20,971,520)      L1/L3 out
  u16*   Tb   = ob + 20971520;               // [.., 21,102,592)
  u16*   Wb1  = ob + 21102592;               // [.., 21,106,688)
  u16*   Wb2  = ob + 21106688;               // [.., 21,123,072)
  u16*   Wb3  = ob + 21123072;               // [.., 21,385,216)
  u16*   Wb4  = ob + 21385216;               // [.., 25,579,520)
  u16*   Xt1  = ob + 25579520;               // [.., 33,968,128) < 134,217,728 ✓
  // Xc3: per-sample, INSIDE sample b's own 65,536-u16 slice of d_out.
  // conv3 stages it fully to LDS before overwriting the slice — race-free.
  u16*   Xc3  = ob;                          // base 0, sample stride 65,536 u16

  // prologue: zero stats + cvt f32->bf16 + repack conv weights (ONE kernel)
  prep<<<6559, 256, 0, stream>>>(partA,
                                 trees, Tb, w1, Wb1, w2, Wb2, w3, Wb3, w4, Wb4,
                                 cw1, Wr1, cw2, Wr2, cw3, Wr3);

  // MLP: gemm(+stats) -> gemm(+selfFinalize+applyA+stats) -> ...
  gemm_nt<64,64,4,1,1,4,false,true,0><<<dim3(32,1), 256, 0, stream>>>(
      Tb, nullptr, Wb1, Ya, nullptr, nullptr, nullptr, part1, 2048, 64, 64);
  gemm_nt<64,64,4,1,1,4,true,true,64><<<dim3(32,4), 256, 0, stream>>>(
      nullptr, Ya, Wb2, Yb, part1, g1, be1, part2, 2048, 256, 64);
  gemm_nt<64,64,4,1,1,4,true,true,256><<<dim3(32,16), 256, 0, stream>>>(
      nullptr, Yb, Wb3, Ya, part2, g2, be2, part3, 2048, 1024, 256);
  gemm_nt<128,128,2,2,4,4,true,true,1024><<<dim3(16,32), 256, 0, stream>>>(
      nullptr, Ya, Wb4, Yb, part3, g3, be3, part4, 2048, 4096, 1024);
  bn_apply4_t<<<2048, 256, 0, stream>>>(Yb, part4, g4, be4, Xt1);

  // tree-conv stack (S samples per block: weight reuse across samples)
  // conv1: Xt1 (d_out) -> Xc2 (ws)
  conv_norm< 64,128,false,4><<< 512, 512, 0, stream>>>(Xt1, 4096, Wr1, cb1, gidx, Xc2, 8192, nullptr);
  // conv2: Xc2 (ws) -> Xc3 slices (d_out, sample-strided 65,536 u16)
  conv_norm<128,256,false,4><<< 512, 512, 0, stream>>>(Xc2, 8192, Wr2, cb2, gidx, Xc3, 65536, nullptr);
  // conv3: Xc3 slices (d_out, staged to LDS first) -> final f32 output (d_out)
  conv_norm<256,512,true ,2><<<1024, 512, 0, stream>>>(Xc3, 65536, Wr3, cb3, gidx, nullptr, 0, outF);
}

// Round 11
// 576.209 us; speedup vs baseline: 1.3164x; 1.0095x over previous
//
#include <hip/hip_runtime.h>

typedef unsigned short u16;
typedef unsigned int   u32;
typedef __attribute__((ext_vector_type(8))) short short8;
typedef __attribute__((ext_vector_type(4))) float f32x4;
typedef __attribute__((ext_vector_type(4))) u16  u16x4;

#define DI __device__ __forceinline__

DI float b2f(u16 v){ return __builtin_bit_cast(float, (u32)v << 16); }
DI u16 f2b(float f){ u32 u = __builtin_bit_cast(u32, f); return (u16)((u + 0x7fffu + ((u >> 16) & 1u)) >> 16); }
DI float lrelu(float v){ return v > 0.f ? v : 0.01f * v; }

// direct global->LDS DMA, 16 B per lane (dest must be lane-contiguous)
DI void gload_lds16(const void* g, void* l){
  __builtin_amdgcn_global_load_lds((const __attribute__((address_space(1))) void*)g,
                                   (__attribute__((address_space(3))) void*)l, 16, 0, 0);
}

// ---------------- prep: zero BN accumulators + f32->bf16 cvt + conv repack -
// Conv weights in MFMA-FRAGMENT-TILED layout (R10: coalesced wave loads).
__global__ __launch_bounds__(256)
void prep(float* __restrict__ partA,
          const float* __restrict__ trees, u16* __restrict__ Tb,
          const float* __restrict__ w1, u16* __restrict__ Wb1,
          const float* __restrict__ w2, u16* __restrict__ Wb2,
          const float* __restrict__ w3, u16* __restrict__ Wb3,
          const float* __restrict__ w4, u16* __restrict__ Wb4,
          const float* __restrict__ cw1, u16* __restrict__ Wr1,
          const float* __restrict__ cw2, u16* __restrict__ Wr2,
          const float* __restrict__ cw3, u16* __restrict__ Wr3)
{
  int loc = blockIdx.x*256 + threadIdx.x;
  if (loc < 10880){ partA[loc] = 0.f; return; }
  loc -= 10880;
  {
    const float* in = nullptr; u16* out = nullptr;
    if      (loc < 32768){ in = trees; out = Tb; }
    else if ((loc -= 32768) < 1024){ in = w1; out = Wb1; }
    else if ((loc -= 1024) < 4096){ in = w2; out = Wb2; }
    else if ((loc -= 4096) < 65536){ in = w3; out = Wb3; }
    else if ((loc -= 65536) < 1048576){ in = w4; out = Wb4; }
    else { loc -= 1048576; goto repack; }
    float4 v = ((const float4*)in)[loc];
    u16x4 o; o[0]=f2b(v.x); o[1]=f2b(v.y); o[2]=f2b(v.z); o[3]=f2b(v.w);
    *(u16x4*)(out + (size_t)loc*4) = o;
    return;
  }
repack:
  {
    const float* w; u16* wr; int C, lgC;
    if      (loc < 24576){ w = cw1; wr = Wr1; C = 64;  lgC = 6; }
    else if ((loc -= 24576) < 98304){ w = cw2; wr = Wr2; C = 128; lgC = 7; }
    else if ((loc -= 98304) < 393216){ w = cw3; wr = Wr3; C = 256; lgC = 8; }
    else return;
    int R   = 3*C;
    int nkb = R >> 5;                 // R/32
    int ci   = loc & 7;
    int lane = (loc >> 3) & 63;
    int blk  = loc >> 9;
    int o_tile = blk / nkb;
    int kbi    = blk - o_tile*nkb;
    int o  = o_tile*16 + (lane & 15);
    int ch = kbi*32 + (lane >> 4)*8 + ci;
    int k  = ch >> lgC;
    int c  = ch & (C-1);
    wr[loc] = f2b(w[(size_t)o*R + c*3 + k]);
  }
}

// ---------------- GEMM (NT): Y[M,N] = A[M,K] * W[N,K]^T, f32 out -----------
// Staging: B always via global_load_lds (16B/lane DMA); A via DMA when
// !APPLYA, else f32-read + BN/lrelu/cvt transform in regs (overlaps barrier).
// APPLYA (KK>0): block self-finalizes prev BN from partPrev into LDS ssl.
// STATS: column sums/sumsq -> atomicAdd into partOut (zeroed in prep).
template<int BM, int BN, int WROWS, int WCOLS, int RT, int CT, bool APPLYA, bool STATS, int KK>
__global__ __launch_bounds__(WROWS*WCOLS*64)
void gemm_nt(const u16* __restrict__ A, const float* __restrict__ Af,
             const u16* __restrict__ W, float* __restrict__ Y,
             const float* __restrict__ partPrev, const float* __restrict__ gP,
             const float* __restrict__ beP, float* __restrict__ partOut,
             int M, int N, int K)
{
  constexpr int NT  = WROWS*WCOLS*64;
  constexpr int ALD = (BM*4)/NT;
  constexpr int BLD = (BN*4)/NT;
  __shared__ __align__(16) u16 As[BM*32];
  __shared__ __align__(16) u16 Bs[BN*32];
  __shared__ float ssl[APPLYA ? 2*KK : 1];
  const int tid  = threadIdx.x;
  const int wave = tid >> 6, lane = tid & 63;
  const int wr = wave / WCOLS, wc = wave % WCOLS;
  const int lrow = lane & 15, kg = lane >> 4;
  const int m0 = blockIdx.x * BM, n0 = blockIdx.y * BN;

  if constexpr (APPLYA){
    for (int k = tid; k < KK; k += NT){
      float s = partPrev[k], s2 = partPrev[KK + k];
      float inv  = 1.f / (float)M;
      float mean = s * inv;
      float var  = fmaxf(s2*inv - mean*mean, 0.f);
      float sc   = gP[k] * rsqrtf(var + 1e-5f);
      ssl[k]      = sc;
      ssl[KK + k] = beP[k] - mean*sc;
    }
    __syncthreads();
  }

  f32x4 acc[RT][CT] = {};
  for (int k0 = 0; k0 < K; k0 += 32) {
    uint4 av[ALD];
    if constexpr (APPLYA){
#pragma unroll
      for (int i = 0; i < ALD; i++){
        int x = tid + i*NT; int row = m0 + (x>>2); int c0 = k0 + (x&3)*8;
        const float* ap = Af + (size_t)row*K + c0;
        float4 f0 = *(const float4*)ap;
        float4 f1 = *(const float4*)(ap + 4);
        u32 p0 = (u32)f2b(lrelu(f0.x*ssl[c0+0] + ssl[KK+c0+0]))
               | ((u32)f2b(lrelu(f0.y*ssl[c0+1] + ssl[KK+c0+1])) << 16);
        u32 p1 = (u32)f2b(lrelu(f0.z*ssl[c0+2] + ssl[KK+c0+2]))
               | ((u32)f2b(lrelu(f0.w*ssl[c0+3] + ssl[KK+c0+3])) << 16);
        u32 p2 = (u32)f2b(lrelu(f1.x*ssl[c0+4] + ssl[KK+c0+4]))
               | ((u32)f2b(lrelu(f1.y*ssl[c0+5] + ssl[KK+c0+5])) << 16);
        u32 p3 = (u32)f2b(lrelu(f1.z*ssl[c0+6] + ssl[KK+c0+6]))
               | ((u32)f2b(lrelu(f1.w*ssl[c0+7] + ssl[KK+c0+7])) << 16);
        av[i] = uint4{p0, p1, p2, p3};
      }
    }
    __syncthreads();                     // previous iteration's LDS reads done
    if constexpr (!APPLYA){
#pragma unroll
      for (int i = 0; i < ALD; i++){
        int x = tid + i*NT;
        gload_lds16(A + (size_t)(m0 + (x>>2))*K + k0 + (x&3)*8, As + (size_t)x*8);
      }
    }
#pragma unroll
    for (int i = 0; i < BLD; i++){
      int x = tid + i*NT;
      gload_lds16(W + (size_t)(n0 + (x>>2))*K + k0 + (x&3)*8, Bs + (size_t)x*8);
    }
    if constexpr (APPLYA){
#pragma unroll
      for (int i = 0; i < ALD; i++){ *(uint4*)(As + (tid + i*NT)*8) = av[i]; }
    }
    __syncthreads();                     // drains DMA vmcnt + ds_writes
    short8 af[RT], bfr[CT];
#pragma unroll
    for (int r = 0; r < RT; r++) af[r]  = *(const short8*)(As + ((wr*RT + r)*16 + lrow)*32 + kg*8);
#pragma unroll
    for (int c = 0; c < CT; c++) bfr[c] = *(const short8*)(Bs + ((wc*CT + c)*16 + lrow)*32 + kg*8);
#pragma unroll
    for (int r = 0; r < RT; r++)
#pragma unroll
      for (int c = 0; c < CT; c++)
        acc[r][c] = __builtin_amdgcn_mfma_f32_16x16x32_bf16(af[r], bfr[c], acc[r][c], 0, 0, 0);
  }
  // C/D: col=lane&15, row=(lane>>4)*4+i  [m89/m91]
#pragma unroll
  for (int r = 0; r < RT; r++)
#pragma unroll
    for (int c = 0; c < CT; c++)
#pragma unroll
      for (int i = 0; i < 4; i++){
        int m = m0 + (wr*RT + r)*16 + kg*4 + i;
        int n = n0 + (wc*CT + c)*16 + lrow;
        Y[(size_t)m*N + n] = acc[r][c][i];
      }

  if constexpr (STATS){
    __shared__ float cs[BN], cs2[BN];
    for (int t = tid; t < BN; t += NT){ cs[t] = 0.f; cs2[t] = 0.f; }
    __syncthreads();
#pragma unroll
    for (int c = 0; c < CT; c++){
      float ls = 0.f, ls2 = 0.f;
#pragma unroll
      for (int r = 0; r < RT; r++)
#pragma unroll
        for (int i = 0; i < 4; i++){ float v = acc[r][c][i]; ls += v; ls2 += v*v; }
      ls  += __shfl_down(ls, 32);  ls  += __shfl_down(ls, 16);
      ls2 += __shfl_down(ls2, 32); ls2 += __shfl_down(ls2, 16);
      if (lane < 16){
        atomicAdd(&cs [(wc*CT + c)*16 + lrow], ls);
        atomicAdd(&cs2[(wc*CT + c)*16 + lrow], ls2);
      }
    }
    __syncthreads();
    for (int t = tid; t < BN; t += NT){
      atomicAdd(partOut + n0 + t,     cs[t]);
      atomicAdd(partOut + N + n0 + t, cs2[t]);
    }
  }
}

// BN apply layer-4 (self-finalized from part4) + per-sample transpose
__global__ __launch_bounds__(256)
void bn_apply4_t(const float* __restrict__ Y, const float* __restrict__ part4,
                 const float* __restrict__ g4, const float* __restrict__ be4,
                 u16* __restrict__ Xt)
{
  const int b = blockIdx.x, tid = threadIdx.x;
  __shared__ float ssl[8192];
  __shared__ u16 t[64*65];
  for (int k = tid; k < 4096; k += 256){
    float s = part4[k], s2 = part4[4096 + k];
    float inv  = 1.f / 2048.f;
    float mean = s * inv;
    float var  = fmaxf(s2*inv - mean*mean, 0.f);
    float sc   = g4[k] * rsqrtf(var + 1e-5f);
    ssl[k]        = sc;
    ssl[4096 + k] = be4[k] - mean*sc;
  }
  __syncthreads();
  for (int j = tid; j < 4096; j += 256){
    float v = Y[(size_t)b*4096 + j];
    v = lrelu(v*ssl[j] + ssl[4096 + j]);
    int c = j >> 6, n = j & 63;
    t[c*65 + n] = f2b(v);
  }
  __syncthreads();
  for (int e = tid; e < 4096; e += 256){
    int n = e >> 6, c = e & 63;
    Xt[(size_t)b*4096 + n*64 + c] = t[c*65 + n];
  }
}

// ---------------- tree-conv + TreeLayerNorm + LeakyReLU --------------------
// S samples per block, 8 waves; fragment-tiled weights (coalesced loads).
template<int C, int O, bool LAST, int S>
__global__ __launch_bounds__(512)
void conv_norm(const u16* __restrict__ Xin, long inStride,
               const u16* __restrict__ Wr,
               const float* __restrict__ cb, const int* __restrict__ gidx,
               u16* __restrict__ Xout, long outStride, float* __restrict__ Outf)
{
  constexpr int R   = 3*C;
  constexpr int CSI = C + 8;
  constexpr int XS  = 65*CSI;          // per-sample LDS stride (u16)
  constexpr int RT  = O/128;
  constexpr int CH8 = C/8;
  __shared__ __align__(16) u16 xs[S*XS];
  __shared__ int idxs[S*192];
  __shared__ float red[S*16];
  __shared__ float res[S*2];
  const int b0 = blockIdx.x * S, tid = threadIdx.x;
  const int wave = tid >> 6, lane = tid & 63;
  const int lrow = lane & 15, kg = lane >> 4;

#pragma unroll
  for (int s = 0; s < S; s++){
    const u16* xg = Xin + (size_t)(b0 + s)*inStride;
    u16* xd = xs + s*XS;
    for (int e = tid; e < 64*CH8; e += 512){
      int row = e / CH8, t = e % CH8;
      *(uint4*)(xd + row*CSI + t*8) = *(const uint4*)(xg + row*C + t*8);
    }
    if (tid < CH8){ uint4 z = {0,0,0,0}; *(uint4*)(xd + 64*CSI + tid*8) = z; }
    if (tid < 189) idxs[s*192 + tid] = gidx[(size_t)(b0 + s)*189 + tid] & 63;
  }
  __syncthreads();

  int jtp[S][4];
#pragma unroll
  for (int s = 0; s < S; s++)
#pragma unroll
    for (int ct = 0; ct < 4; ct++){
      int n = ct*16 + lrow;
      if (n == 0) jtp[s][ct] = 64 | (64<<7) | (64<<14);
      else        jtp[s][ct] = idxs[s*192 + 3*(n-1) + 0]
                             | (idxs[s*192 + 3*(n-1) + 1] << 7)
                             | (idxs[s*192 + 3*(n-1) + 2] << 14);
    }

  // per-wave weight bases (fragment-tiled layout)
  size_t wb[RT];
#pragma unroll
  for (int r = 0; r < RT; r++) wb[r] = (size_t)(wave + 8*r)*R*16 + lane*8;

  f32x4 acc[RT][4][S] = {};
#pragma unroll
  for (int k = 0; k < 3; k++){
    int rb[S][4];
#pragma unroll
    for (int s = 0; s < S; s++)
#pragma unroll
      for (int ct = 0; ct < 4; ct++)
        rb[s][ct] = s*XS + ((jtp[s][ct] >> (7*k)) & 127)*CSI + kg*8;
#pragma unroll 2
    for (int cc = 0; cc < C; cc += 32){
      const int choff = (k*C + cc)*16;
      short8 af[RT];
#pragma unroll
      for (int r = 0; r < RT; r++)
        af[r] = *(const short8*)(Wr + wb[r] + choff);
#pragma unroll
      for (int s = 0; s < S; s++){
        short8 bfr[4];
#pragma unroll
        for (int ct = 0; ct < 4; ct++)
          bfr[ct] = *(const short8*)(xs + rb[s][ct] + cc);
#pragma unroll
        for (int r = 0; r < RT; r++)
#pragma unroll
          for (int ct = 0; ct < 4; ct++)
            acc[r][ct][s] = __builtin_amdgcn_mfma_f32_16x16x32_bf16(af[r], bfr[ct], acc[r][ct][s], 0, 0, 0);
      }
    }
  }

  float sv[S], sv2[S];
#pragma unroll
  for (int s = 0; s < S; s++){ sv[s] = 0.f; sv2[s] = 0.f; }
#pragma unroll
  for (int r = 0; r < RT; r++)
#pragma unroll
    for (int i = 0; i < 4; i++){
      int o = (wave + 8*r)*16 + kg*4 + i;
      float bias = cb[o];
#pragma unroll
      for (int ct = 0; ct < 4; ct++){
        int n = ct*16 + lrow;
#pragma unroll
        for (int s = 0; s < S; s++){
          float v = acc[r][ct][s][i];
          if (n != 0) v += bias;
          acc[r][ct][s][i] = v;
          sv[s] += v; sv2[s] += v*v;
        }
      }
    }
#pragma unroll
  for (int s = 0; s < S; s++){
#pragma unroll
    for (int off = 32; off > 0; off >>= 1){ sv[s] += __shfl_down(sv[s], off); sv2[s] += __shfl_down(sv2[s], off); }
    if (lane == 0){ red[s*16 + wave] = sv[s]; red[s*16 + 8 + wave] = sv2[s]; }
  }
  __syncthreads();
  if (tid < S){
    float Sm = 0.f, S2 = 0.f;
    for (int w = 0; w < 8; w++){ Sm += red[tid*16 + w]; S2 += red[tid*16 + 8 + w]; }
    const float NV = (float)(O*64);
    float mean = Sm / NV;
    float var  = fmaxf(S2/NV - mean*mean, 0.f) * (NV/(NV-1.f));  // torch.std ddof=1
    float sc   = 1.f / (sqrtf(var) + 1e-5f);
    res[tid*2 + 0] = mean; res[tid*2 + 1] = sc;
  }
  __syncthreads();

#pragma unroll
  for (int s = 0; s < S; s++){
    const float mean = res[s*2 + 0], sc = res[s*2 + 1];
    if constexpr (LAST) {
#pragma unroll
      for (int r = 0; r < RT; r++)
#pragma unroll
        for (int ct = 0; ct < 4; ct++)
#pragma unroll
          for (int i = 0; i < 4; i++){
            int o = (wave + 8*r)*16 + kg*4 + i;
            int n = ct*16 + lrow;
            Outf[(size_t)(b0 + s)*(O*64) + o*64 + n] = lrelu((acc[r][ct][s][i] - mean)*sc);
          }
    } else {
#pragma unroll
      for (int r = 0; r < RT; r++)
#pragma unroll
        for (int ct = 0; ct < 4; ct++){
          int o0 = (wave + 8*r)*16 + kg*4;
          int n  = ct*16 + lrow;
          u16x4 pk;
#pragma unroll
          for (int i = 0; i < 4; i++) pk[i] = f2b(lrelu((acc[r][ct][s][i] - mean)*sc));
          *(u16x4*)(Xout + (size_t)(b0 + s)*outStride + (size_t)n*O + o0) = pk;
        }
    }
  }
}

// ---------------------------------------------------------------------------
extern "C" void kernel_launch(void* const* d_in, const int* in_sizes, int n_in,
                              void* d_out, int out_size, void* d_ws, size_t ws_size,
                              hipStream_t stream)
{
  // ALL float inputs are float32 (proven by R3's dtype-flag experiment).
  const float* trees = (const float*)d_in[0];
  const int*   gidx  = (const int*)d_in[1];
  const float* w1 = (const float*)d_in[2];
  const float* g1 = (const float*)d_in[4];  const float* be1 = (const float*)d_in[5];
  const float* w2 = (const float*)d_in[6];
  const float* g2 = (const float*)d_in[8];  const float* be2 = (const float*)d_in[9];
  const float* w3 = (const float*)d_in[10];
  const float* g3 = (const float*)d_in[12]; const float* be3 = (const float*)d_in[13];
  const float* w4 = (const float*)d_in[14];
  const float* g4 = (const float*)d_in[16]; const float* be4 = (const float*)d_in[17];
  const float* cw1 = (const float*)d_in[18]; const float* cb1 = (const float*)d_in[19];
  const float* cw2 = (const float*)d_in[20]; const float* cb2 = (const float*)d_in[21];
  const float* cw3 = (const float*)d_in[22]; const float* cb3 = (const float*)d_in[23];
  // linear biases b1..b4 cancel under training-mode BN — unused.

  // ws (~33.3 MiB): repacked conv weights + BN stat accumulators + Xc2.
  char* ws = (char*)d_ws;
  size_t off = 0;
  auto alloc = [&](size_t bytes)->char*{ char* p = ws + off; off += (bytes + 255) & ~(size_t)255; return p; };
  u16*   Wr1  = (u16*)  alloc(128*192*2);
  u16*   Wr2  = (u16*)  alloc(256*384*2);
  u16*   Wr3  = (u16*)  alloc(512*768*2);
  float* partA= (float*)alloc(2*(64+256+1024+4096)*4);
  u16*   Xc2  = (u16*)  alloc((size_t)2048*64*128*2);   // 32 MiB
  float* part1 = partA;             // 128 floats
  float* part2 = part1 + 2*64;      // 512
  float* part3 = part2 + 2*256;     // 2048
  float* part4 = part3 + 2*1024;    // 8192

  // d_out is (2048,512,64) FLOAT32 = 256 MiB. MLP-phase scratch inside it.
  float* outF = (float*)d_out;
  u16*   ob   = (u16*)d_out;                 // u16-unit view for offsets
  float* Yb   = (float*)ob;                  // [0, 16,777,216)   L2/L4 out
  float* Ya   = (float*)(ob + 16777216);     // [.., 20,971,520)  L1/L3 out
  u16*   Tb   = ob + 20971520;
  u16*   Wb1  = ob + 21102592;
  u16*   Wb2  = ob + 21106688;
  u16*   Wb3  = ob + 21123072;
  u16*   Wb4  = ob + 21385216;
  u16*   Xt1  = ob + 25579520;               // [.., 33,968,128)
  // Xc3: per-sample, inside sample b's own 65,536-u16 slice of d_out.
  u16*   Xc3  = ob;                          // stride 65,536 u16

  prep<<<6559, 256, 0, stream>>>(partA,
                                 trees, Tb, w1, Wb1, w2, Wb2, w3, Wb3, w4, Wb4,
                                 cw1, Wr1, cw2, Wr2, cw3, Wr3);

  // MLP: gemm(+stats) -> gemm(+selfFinalize+applyA+stats) -> ...
  gemm_nt<64,64,4,1,1,4,false,true,0><<<dim3(32,1), 256, 0, stream>>>(
      Tb, nullptr, Wb1, Ya, nullptr, nullptr, nullptr, part1, 2048, 64, 64);
  gemm_nt<64,64,4,1,1,4,true,true,64><<<dim3(32,4), 256, 0, stream>>>(
      nullptr, Ya, Wb2, Yb, part1, g1, be1, part2, 2048, 256, 64);
  gemm_nt<64,64,4,1,1,4,true,true,256><<<dim3(32,16), 256, 0, stream>>>(
      nullptr, Yb, Wb3, Ya, part2, g2, be2, part3, 2048, 1024, 256);
  // gemm4: 128x256 tile (512 thr) -> APPLYA redundancy 32x -> 16x
  gemm_nt<128,256,2,4,4,4,true,true,1024><<<dim3(16,16), 512, 0, stream>>>(
      nullptr, Ya, Wb4, Yb, part3, g3, be3, part4, 2048, 4096, 1024);
  bn_apply4_t<<<2048, 256, 0, stream>>>(Yb, part4, g4, be4, Xt1);

  // tree-conv stack (unchanged from R10 — control)
  conv_norm< 64,128,false,4><<< 512, 512, 0, stream>>>(Xt1, 4096, Wr1, cb1, gidx, Xc2, 8192, nullptr);
  conv_norm<128,256,false,4><<< 512, 512, 0, stream>>>(Xc2, 8192, Wr2, cb2, gidx, Xc3, 65536, nullptr);
  conv_norm<256,512,true ,2><<<1024, 512, 0, stream>>>(Xc3, 65536, Wr3, cb3, gidx, nullptr, 0, outF);
}